// Round 10
// baseline (481.948 us; speedup 1.0000x reference)
//
#include <hip/hip_runtime.h>
#include <hip/hip_bf16.h>

#define IN_DIM  128
#define OUT_DIM 64
#define SCAN_CHUNK 1024   // 256 threads x 4 elems

// ---------------------------------------------------------------------------
// Prologue: degree histogram (also records per-edge rank) -> exclusive scan
// ---------------------------------------------------------------------------
__global__ void k_zero(unsigned* __restrict__ p, int n) {
    int i = blockIdx.x * blockDim.x + threadIdx.x;
    if (i < n) p[i] = 0u;
}

// rank[e] = number of earlier edges with same dst (atomic order; any perm ok)
__global__ void k_hist2(const int* __restrict__ dst, unsigned* __restrict__ cnt,
                        unsigned short* __restrict__ rank, int nE) {
    int e = blockIdx.x * blockDim.x + threadIdx.x;
    if (e < nE) {
        unsigned k = atomicAdd(&cnt[dst[e]], 1u);
        rank[e] = (unsigned short)k;       // sequential write
    }
}

__global__ __launch_bounds__(256) void k_scanA(const unsigned* __restrict__ cnt,
                                               unsigned* __restrict__ offs,
                                               unsigned* __restrict__ partials,
                                               float* __restrict__ dinv, int n) {
    __shared__ unsigned sums[256];
    int base = blockIdx.x * SCAN_CHUNK + threadIdx.x * 4;
    unsigned v[4]; unsigned s = 0;
#pragma unroll
    for (int k = 0; k < 4; ++k) {
        int i = base + k;
        unsigned c = (i < n) ? cnt[i] : 0u;
        if (i < n) dinv[i] = rsqrtf((float)c + 1.0f);   // +1 self-loop
        v[k] = s; s += c;
    }
    sums[threadIdx.x] = s;
    __syncthreads();
    for (int d = 1; d < 256; d <<= 1) {
        unsigned t = (threadIdx.x >= (unsigned)d) ? sums[threadIdx.x - d] : 0u;
        __syncthreads();
        sums[threadIdx.x] += t;
        __syncthreads();
    }
    unsigned excl = sums[threadIdx.x] - s;
#pragma unroll
    for (int k = 0; k < 4; ++k) {
        int i = base + k;
        if (i < n) offs[i] = excl + v[k];
    }
    if (threadIdx.x == 255) partials[blockIdx.x] = sums[255];
}

__global__ void k_scanB(unsigned* __restrict__ partials, int nb) {
    __shared__ unsigned s[256];
    unsigned v = (threadIdx.x < (unsigned)nb) ? partials[threadIdx.x] : 0u;
    s[threadIdx.x] = v;
    __syncthreads();
    for (int d = 1; d < 256; d <<= 1) {
        unsigned t = (threadIdx.x >= (unsigned)d) ? s[threadIdx.x - d] : 0u;
        __syncthreads();
        s[threadIdx.x] += t;
        __syncthreads();
    }
    if (threadIdx.x < (unsigned)nb) partials[threadIdx.x] = s[threadIdx.x] - v;
}

__global__ void k_scanC(unsigned* __restrict__ offs, const unsigned* __restrict__ partials,
                        int n) {
    int i = blockIdx.x * blockDim.x + threadIdx.x;
    if (i < n) offs[i] += partials[i / SCAN_CHUNK];
}

// ---------------------------------------------------------------------------
// Weight transpose: Wt[c][k] = W[k][c]  (one-time, 8K+4K elements)
// ---------------------------------------------------------------------------
__global__ void k_wt(const float* __restrict__ W1, const float* __restrict__ W2,
                     float* __restrict__ Wt1, float* __restrict__ Wt2) {
    int i = blockIdx.x * blockDim.x + threadIdx.x;
    if (i < IN_DIM * 64) {
        int k = i >> 6, c = i & 63;
        Wt1[c * IN_DIM + k] = W1[i];     // coalesced read, scattered write
    }
    if (i < OUT_DIM * 64) {
        int k = i >> 6, c = i & 63;
        Wt2[c * OUT_DIM + k] = W2[i];
    }
}

// ---------------------------------------------------------------------------
// Atomic-free edge scatter (LDS-free, high occupancy hides write latency)
// ---------------------------------------------------------------------------
__global__ void k_scat(const int* __restrict__ src, const int* __restrict__ dst,
                       const unsigned short* __restrict__ rank,
                       const unsigned* __restrict__ offs,
                       int* __restrict__ perm, int nE) {
    int e = blockIdx.x * blockDim.x + threadIdx.x;
    if (e < nE) {
        unsigned p = offs[dst[e]] + (unsigned)rank[e];
        __builtin_nontemporal_store(src[e], &perm[p]);
    }
}

// ---------------------------------------------------------------------------
// Linear layer, transposed orientation: lane = row (64 rows/wave).
// Row lives in VGPRs (xr[KD], fully unrolled); W read as WAVE-UNIFORM loads
// of pre-transposed Wt[c][k] (contiguous per output column -> s_load/K$).
// Zero LDS, zero barriers. Per-lane loads/stores are line-dense; L1/L2 merge.
// RELU: relu(dinv*in) applied on row load (layer-2 input); output scaled dinv.
// ---------------------------------------------------------------------------
template <int KD, bool RELU>
__global__ __launch_bounds__(256) void k_linT(const float* __restrict__ in,
                                              const float* __restrict__ Wt,   // [64][KD]
                                              const float* __restrict__ dinv,
                                              float* __restrict__ outp, int n) {
    int lane = threadIdx.x & 63;
    int row  = (blockIdx.x * 4 + (threadIdx.x >> 6)) * 64 + lane;
    bool valid = row < n;
    int rr = valid ? row : (n - 1);          // dup-tail read, store masked
    float dv = dinv[rr];

    float xr[KD];                            // full row in registers
    {
        const float4* rp = (const float4*)(in + (size_t)rr * KD);
#pragma unroll
        for (int q = 0; q < KD / 4; ++q) {
            float4 v = rp[q];                // per-lane contiguous 16B
            if (RELU) {
                v.x = fmaxf(dv * v.x, 0.f); v.y = fmaxf(dv * v.y, 0.f);
                v.z = fmaxf(dv * v.z, 0.f); v.w = fmaxf(dv * v.w, 0.f);
            }
            xr[4 * q + 0] = v.x; xr[4 * q + 1] = v.y;
            xr[4 * q + 2] = v.z; xr[4 * q + 3] = v.w;
        }
    }

    float4* op = (float4*)(outp + (size_t)rr * 64);
#pragma unroll 1
    for (int cg = 0; cg < 16; ++cg) {        // 4 output columns per iteration
        const float* w0 = Wt + (size_t)(4 * cg) * KD;
        const float* w1 = w0 + KD;
        const float* w2 = w1 + KD;
        const float* w3 = w2 + KD;
        float a0 = 0.f, a1 = 0.f, a2 = 0.f, a3 = 0.f;
#pragma unroll
        for (int k = 0; k < KD; ++k) {
            float xv = xr[k];
            a0 += xv * w0[k];                // wave-uniform W operand
            a1 += xv * w1[k];
            a2 += xv * w2[k];
            a3 += xv * w3[k];
        }
        if (valid) op[cg] = float4{dv * a0, dv * a1, dv * a2, dv * a3};
    }
}

// ---------------------------------------------------------------------------
// CSR gather, 8-way ILP: one wave per node, lane = feature dim.
// acc = hs[r] (self-loop) + sum over neighbors; FIN applies final dinv[r].
// ---------------------------------------------------------------------------
template <bool FIN>
__global__ __launch_bounds__(256) void k_gather(const float* __restrict__ hs,
                                                const unsigned* __restrict__ offs,
                                                const int* __restrict__ perm,
                                                const float* __restrict__ dinv,
                                                float* __restrict__ outb,
                                                int n, int nE) {
    int lane = threadIdx.x & 63;
    int r = blockIdx.x * 4 + (threadIdx.x >> 6);
    if (r >= n) return;
    unsigned beg = offs[r];
    unsigned end = (r + 1 < n) ? offs[r + 1] : (unsigned)nE;
    float a0 = hs[(size_t)r * 64 + lane];            // self-loop term
    float a1 = 0.f, a2 = 0.f, a3 = 0.f, a4 = 0.f, a5 = 0.f, a6 = 0.f, a7 = 0.f;
    for (unsigned e0 = beg; e0 < end; e0 += 64) {
        unsigned c = min(64u, end - e0);
        int sl = (lane < (int)c) ? perm[e0 + lane] : 0;   // coalesced edge read
        unsigned k = 0;
        for (; k + 8 <= c; k += 8) {
            int s0 = __shfl(sl, (int)k);
            int s1 = __shfl(sl, (int)k + 1);
            int s2 = __shfl(sl, (int)k + 2);
            int s3 = __shfl(sl, (int)k + 3);
            int s4 = __shfl(sl, (int)k + 4);
            int s5 = __shfl(sl, (int)k + 5);
            int s6 = __shfl(sl, (int)k + 6);
            int s7 = __shfl(sl, (int)k + 7);
            float v0 = hs[(size_t)s0 * 64 + lane];
            float v1 = hs[(size_t)s1 * 64 + lane];
            float v2 = hs[(size_t)s2 * 64 + lane];
            float v3 = hs[(size_t)s3 * 64 + lane];
            float v4 = hs[(size_t)s4 * 64 + lane];
            float v5 = hs[(size_t)s5 * 64 + lane];
            float v6 = hs[(size_t)s6 * 64 + lane];
            float v7 = hs[(size_t)s7 * 64 + lane];
            a0 += v0; a1 += v1; a2 += v2; a3 += v3;
            a4 += v4; a5 += v5; a6 += v6; a7 += v7;
        }
        for (; k + 4 <= c; k += 4) {
            int s0 = __shfl(sl, (int)k);
            int s1 = __shfl(sl, (int)k + 1);
            int s2 = __shfl(sl, (int)k + 2);
            int s3 = __shfl(sl, (int)k + 3);
            float v0 = hs[(size_t)s0 * 64 + lane];
            float v1 = hs[(size_t)s1 * 64 + lane];
            float v2 = hs[(size_t)s2 * 64 + lane];
            float v3 = hs[(size_t)s3 * 64 + lane];
            a0 += v0; a1 += v1; a2 += v2; a3 += v3;
        }
        for (; k < c; ++k) {
            int s = __shfl(sl, (int)k);
            a0 += hs[(size_t)s * 64 + lane];
        }
    }
    float acc = ((a0 + a1) + (a2 + a3)) + ((a4 + a5) + (a6 + a7));
    if (FIN) acc *= dinv[r];
    outb[(size_t)r * 64 + lane] = acc;
}

// ---------------------------------------------------------------------------
extern "C" void kernel_launch(void* const* d_in, const int* in_sizes, int n_in,
                              void* d_out, int out_size, void* d_ws, size_t ws_size,
                              hipStream_t stream) {
    const float* x  = (const float*)d_in[0];
    const int*   ei = (const int*)d_in[1];
    const float* W1 = (const float*)d_in[2];
    const float* W2 = (const float*)d_in[3];
    float* out = (float*)d_out;

    int n  = in_sizes[0] / IN_DIM;   // 100000
    int nE = in_sizes[1] / 2;        // 1600000
    const int* src = ei;
    const int* dst = ei + nE;

    // workspace carve-up (256B-aligned); d_out doubles as the layer-1 agg buffer
    char* w = (char*)d_ws;
    size_t nAl = ((size_t)n * 4 + 255) & ~(size_t)255;
    float*          dinv     = (float*)w;          w += nAl;
    unsigned*       cnt      = (unsigned*)w;       w += nAl;
    unsigned*       offs     = (unsigned*)w;       w += nAl;
    unsigned*       partials = (unsigned*)w;       w += 4096;
    float*          Wt1      = (float*)w;          w += IN_DIM * 64 * 4;
    float*          Wt2      = (float*)w;          w += OUT_DIM * 64 * 4;
    unsigned short* rank     = (unsigned short*)w; w += ((size_t)nE * 2 + 255) & ~(size_t)255;
    int*            perm     = (int*)w;            w += ((size_t)nE * 4 + 255) & ~(size_t)255;
    float*          hs       = (float*)w;          w += (size_t)n * 64 * 4;
    float*          agg      = out;                // layer-1 aggregate lives in d_out

    int nb   = (n + SCAN_CHUNK - 1) / SCAN_CHUNK;
    int gE   = (nE + 255) / 256;
    int gN   = (n + 255) / 256;
    int gRow = (n + 3) / 4;
    int gLin = (n + 255) / 256;      // 256 rows per block (4 waves x 64 rows)

    // --- prologue: weight transpose, degrees + per-edge ranks, node offsets ---
    k_wt<<<(IN_DIM * 64 + 255) / 256, 256, 0, stream>>>(W1, W2, Wt1, Wt2);
    k_zero<<<gN, 256, 0, stream>>>(cnt, n);
    k_hist2<<<gE, 256, 0, stream>>>(dst, cnt, rank, nE);
    k_scanA<<<nb, 256, 0, stream>>>(cnt, offs, partials, dinv, n);
    k_scanB<<<1, 256, 0, stream>>>(partials, nb);
    k_scanC<<<gN, 256, 0, stream>>>(offs, partials, n);

    // --- layer 1 ---
    k_linT<IN_DIM, false><<<gLin, 256, 0, stream>>>(x, Wt1, dinv, hs, n);
    k_scat<<<gE, 256, 0, stream>>>(src, dst, rank, offs, perm, nE);
    k_gather<false><<<gRow, 256, 0, stream>>>(hs, offs, perm, dinv, agg, n, nE);

    // --- layer 2 (reuse hs for hs2; final dinv folded into gather) ---
    k_linT<OUT_DIM, true><<<gLin, 256, 0, stream>>>(agg, Wt2, dinv, hs, n);
    k_gather<true><<<gRow, 256, 0, stream>>>(hs, offs, perm, dinv, out, n, nE);
}